// Round 1
// 661.338 us; speedup vs baseline: 1.3798x; 1.3798x over previous
//
#include <hip/hip_runtime.h>
#include <cstdint>

typedef __bf16 bf16;
typedef bf16 bf16x4 __attribute__((ext_vector_type(4)));
typedef bf16 bf16x8 __attribute__((ext_vector_type(8)));
typedef float f32x4 __attribute__((ext_vector_type(4)));

// ---------------------------------------------------------------------------
// K1: fused separable 12-tap FIR downsample 512->256 (stride 2, pad 5, zeros)
//     + transpose-pack to NHWC bf16.
// Block tile: 16 output rows x 64 output cols, loop over 32 channels.
// taps: tv[j] = f2d[j][0], th[i] = f2d[0][i]/f2d[0][0]  (tv[j]*th[i]==f2d[j][i])
// out: hmd [524288 pixels][32 ch] bf16,  pixel = (b*256+y)*256+x
// ---------------------------------------------------------------------------
__global__ __launch_bounds__(256) void k1_fused(const float* __restrict__ hm,
                                                const float* __restrict__ f2d,
                                                bf16* __restrict__ hmd) {
    __shared__ float in_t[42 * 144];   // 24,192 B  input tile (zero-padded)
    __shared__ float v_t[16 * 144];    //  9,216 B  after vertical pass
    __shared__ bf16  out_t[8 * 1024];  // 16,384 B  8-channel transpose buffer
    // total 49,792 B -> 3 blocks/CU

    const int tid = threadIdx.x;
    const int bid = blockIdx.x;        // 512 = b(8) x yt(16) x xt(4)
    const int xt = bid & 3;
    const int yt = (bid >> 2) & 15;
    const int b  = bid >> 6;
    const int y0 = yt * 16;            // output row base
    const int x0 = xt * 64;            // output col base
    const int R0 = 2 * y0 - 5;         // input row of tile row 0
    const int B0 = 2 * x0 - 8;         // input col of tile col 0 (16B aligned)

    float tv[12], th[12];
    const float inv = 1.0f / f2d[0];
#pragma unroll
    for (int j = 0; j < 12; ++j) { tv[j] = f2d[j * 12]; th[j] = f2d[j] * inv; }

    const float* srcb = hm + (size_t)b * 32 * 262144;

#pragma unroll 1
    for (int c = 0; c < 32; ++c) {
        const float* sc = srcb + (size_t)c * 262144;

        // ---- stage 42x144 f32 tile, zero-filled OOB (matches zero padding) ----
        // 42*36 = 1512 float4 chunks
#pragma unroll
        for (int k = 0; k < 6; ++k) {
            int idx = k * 256 + tid;
            if (idx < 1512) {
                int R = idx / 36;
                int q = idx - R * 36;
                int gr = R0 + R;
                int gc = B0 + 4 * q;           // always 16B aligned; OOB is all-or-nothing
                f32x4 vv = {0.f, 0.f, 0.f, 0.f};
                if ((unsigned)gr < 512u && (unsigned)gc < 512u)
                    vv = *(const f32x4*)(sc + gr * 512 + gc);
                *(f32x4*)(in_t + R * 144 + 4 * q) = vv;
            }
        }
        __syncthreads();

        // ---- vertical FIR: 2 output rows per thread-chunk (rows share 10/12 taps)
        // 8 row-pairs x 36 col-chunks = 288 chunks
#pragma unroll
        for (int s = 0; s < 2; ++s) {
            int idx = s * 256 + tid;
            if (idx < 288) {
                int yp = idx / 36;             // row pair 0..7
                int q  = idx - yp * 36;
                const float* col = in_t + 4 * q;
                f32x4 a0 = {0.f, 0.f, 0.f, 0.f};
                f32x4 a1 = {0.f, 0.f, 0.f, 0.f};
#pragma unroll
                for (int r = 0; r < 14; ++r) {
                    f32x4 rv = *(const f32x4*)(col + (4 * yp + r) * 144);
                    if (r < 12)  a0 += tv[r] * rv;
                    if (r >= 2)  a1 += tv[r - 2] * rv;
                }
                *(f32x4*)(v_t + (2 * yp) * 144 + 4 * q) = a0;
                *(f32x4*)(v_t + (2 * yp + 1) * 144 + 4 * q) = a1;
            }
        }
        __syncthreads();

        // ---- horizontal FIR: 2 output cols per thread (share 10/12 taps) ----
        // 16 rows x 32 col-pairs = 512
        bf16* oc = out_t + (c & 7) * 1024;
#pragma unroll
        for (int s = 0; s < 2; ++s) {
            int idx = s * 256 + tid;
            int yo = idx >> 5;
            int xp = idx & 31;
            int xo = 2 * xp;
            const float* vr = v_t + yo * 144 + 4 * xp + 3;  // col C0 = 2*xo+3
            float a0 = 0.f, a1 = 0.f;
#pragma unroll
            for (int r = 0; r < 14; ++r) {
                float vv = vr[r];
                if (r < 12)  a0 += th[r] * vv;
                if (r >= 2)  a1 += th[r - 2] * vv;
            }
            unsigned lo = __builtin_bit_cast(unsigned short, (bf16)a0);
            unsigned hi = __builtin_bit_cast(unsigned short, (bf16)a1);
            *(unsigned int*)(oc + yo * 64 + xo) = lo | (hi << 16);
        }

        // ---- every 8 channels: transpose-pack + 16B NHWC burst ----
        if ((c & 7) == 7) {
            __syncthreads();
            int ph = c >> 3;                    // 0..3
            const unsigned short* Ts = (const unsigned short*)out_t;
#pragma unroll
            for (int s = 0; s < 4; ++s) {
                int pix = s * 256 + tid;        // 0..1023
                int yo = pix >> 6;
                int xo = pix & 63;
                unsigned int u[4];
#pragma unroll
                for (int g = 0; g < 4; ++g) {
                    unsigned lo = Ts[(2 * g) * 1024 + pix];
                    unsigned hi = Ts[(2 * g + 1) * 1024 + pix];
                    u[g] = lo | (hi << 16);
                }
                size_t p = ((size_t)(b * 256 + y0 + yo) * 256) + x0 + xo;
                *(uint4*)(hmd + p * 32 + ph * 8) = make_uint4(u[0], u[1], u[2], u[3]);
            }
        }
        __syncthreads();
    }
}

// ---------------------------------------------------------------------------
// K0: weights -> bf16.  wsb[n][k] n<128,k<32 ; wcat[n][k] n<128,k<128
// ---------------------------------------------------------------------------
__global__ __launch_bounds__(256) void k0_prep(const float* __restrict__ w_shared,
                                               const float* __restrict__ w_gamma,
                                               const float* __restrict__ w_beta,
                                               bf16* __restrict__ wsb,
                                               bf16* __restrict__ wcat) {
    int t = blockIdx.x * 256 + threadIdx.x;   // 16384 total
    if (t < 4096) wsb[t] = (bf16)w_shared[t];
    int n = t >> 7, k = t & 127;
    float wv = (n < 64) ? w_gamma[n * 128 + k] : w_beta[(n - 64) * 128 + k];
    wcat[t] = (bf16)wv;
}

// ---------------------------------------------------------------------------
// K2: InstanceNorm stats. one block per (b,c); 65536 elems.
// ---------------------------------------------------------------------------
__global__ __launch_bounds__(256) void k2_stats(const float* __restrict__ x,
                                                float* __restrict__ meanp,
                                                float* __restrict__ rstdp) {
    int bc = blockIdx.x;
    const float* p = x + (size_t)bc * 65536;
    int tid = threadIdx.x;
    float s = 0.f, s2 = 0.f;
#pragma unroll 4
    for (int i = 0; i < 64; ++i) {
        f32x4 vv = *(const f32x4*)(p + (i * 256 + tid) * 4);
        s += vv[0] + vv[1] + vv[2] + vv[3];
        s2 += vv[0] * vv[0] + vv[1] * vv[1] + vv[2] * vv[2] + vv[3] * vv[3];
    }
#pragma unroll
    for (int off = 32; off > 0; off >>= 1) {
        s += __shfl_down(s, off);
        s2 += __shfl_down(s2, off);
    }
    __shared__ float red[8];
    int w = tid >> 6, lane = tid & 63;
    if (lane == 0) { red[w] = s; red[4 + w] = s2; }
    __syncthreads();
    if (tid == 0) {
        float S = red[0] + red[1] + red[2] + red[3];
        float S2 = red[4] + red[5] + red[6] + red[7];
        float mu = S * (1.f / 65536.f);
        float var = S2 * (1.f / 65536.f) - mu * mu;
        meanp[bc] = mu;
        rstdp[bc] = rsqrtf(var + 1e-5f);
    }
}

// ---------------------------------------------------------------------------
// K3: fused  h = lrelu(U*Ws^T + bs)*sqrt2 ; [gamma|beta] = h*Wcat^T + bias ;
//            out = (x-mu)*rstd*(1+gamma) + beta + 0.1*x
// ---------------------------------------------------------------------------
__global__ __launch_bounds__(256) void k3_fused(
    const bf16* __restrict__ hmd, const bf16* __restrict__ wsb,
    const bf16* __restrict__ wcat, const float* __restrict__ bsh,
    const float* __restrict__ bga, const float* __restrict__ bbe,
    const float* __restrict__ x, const float* __restrict__ meanp,
    const float* __restrict__ rstdp, float* __restrict__ out) {
    constexpr int HROW = 136;                 // bf16 units; 272B rows, 16B-aligned frags
    __shared__ bf16 buf[4 * 4608];            // per-wave: H[32][136] then GB[128][36]
    __shared__ float smean[64], srstd[64];

    const int tid = threadIdx.x;
    const int w = tid >> 6;
    const int lane = tid & 63;
    const int l15 = lane & 15;
    const int quad = lane >> 4;

    const int bid = blockIdx.x;               // 4096 blocks
    const int b = bid >> 9;
    const int y = (bid >> 1) & 255;
    const int x0 = (bid & 1) << 7;

    if (tid < 64) {
        smean[tid] = meanp[b * 64 + tid];
        srstd[tid] = rstdp[b * 64 + tid];
    }

    bf16* Hw = buf + w * 4608;
    const int pw = bid * 128 + w * 32;        // wave's pixel base

    // ---- GEMM1: K=32, one MFMA per (mt,nt) tile ----
    bf16x8 a1[2];
#pragma unroll
    for (int mt = 0; mt < 2; ++mt)
        a1[mt] = *(const bf16x8*)(hmd + (size_t)(pw + mt * 16 + l15) * 32 + quad * 8);
    bf16x8 b1[8];
#pragma unroll
    for (int nt = 0; nt < 8; ++nt)
        b1[nt] = *(const bf16x8*)(wsb + (nt * 16 + l15) * 32 + quad * 8);
    f32x4 zero4 = {0.f, 0.f, 0.f, 0.f};
    f32x4 acc[2][8];
#pragma unroll
    for (int mt = 0; mt < 2; ++mt)
#pragma unroll
        for (int nt = 0; nt < 8; ++nt)
            acc[mt][nt] = __builtin_amdgcn_mfma_f32_16x16x32_bf16(a1[mt], b1[nt], zero4, 0, 0, 0);

    // bias + lrelu*sqrt2 -> H in LDS (C-frag -> A-frag layout transform)
#pragma unroll
    for (int nt = 0; nt < 8; ++nt) {
        float bs = bsh[nt * 16 + l15];
#pragma unroll
        for (int mt = 0; mt < 2; ++mt) {
#pragma unroll
            for (int r = 0; r < 4; ++r) {
                float hv = acc[mt][nt][r] + bs;
                hv = (hv >= 0.f ? hv : 0.2f * hv) * 1.41421356237309515f;
                int m = mt * 16 + quad * 4 + r;
                Hw[m * HROW + nt * 16 + l15] = (bf16)hv;
            }
        }
    }

    // ---- GEMM2: K=128 over 4 kt steps ----
    f32x4 acc2[2][8];
#pragma unroll
    for (int mt = 0; mt < 2; ++mt)
#pragma unroll
        for (int nt = 0; nt < 8; ++nt) acc2[mt][nt] = zero4;
#pragma unroll 1
    for (int kt = 0; kt < 4; ++kt) {
        bf16x8 b2[8];
#pragma unroll
        for (int nt = 0; nt < 8; ++nt)
            b2[nt] = *(const bf16x8*)(wcat + (nt * 16 + l15) * 128 + kt * 32 + quad * 8);
        bf16x8 a2[2];
#pragma unroll
        for (int mt = 0; mt < 2; ++mt)
            a2[mt] = *(const bf16x8*)(Hw + (mt * 16 + l15) * HROW + kt * 32 + quad * 8);
#pragma unroll
        for (int mt = 0; mt < 2; ++mt)
#pragma unroll
            for (int nt = 0; nt < 8; ++nt)
                acc2[mt][nt] = __builtin_amdgcn_mfma_f32_16x16x32_bf16(a2[mt], b2[nt], acc2[mt][nt], 0, 0, 0);
    }

    // gamma/beta (+bias) -> LDS bf16, layout GB[c][px_in_wave], row stride 36
#pragma unroll
    for (int nt = 0; nt < 8; ++nt) {
        int n = nt * 16 + l15;
        float bias = (n < 64) ? bga[n] : bbe[n - 64];
#pragma unroll
        for (int mt = 0; mt < 2; ++mt) {
            bf16x4 pk;
#pragma unroll
            for (int r = 0; r < 4; ++r) pk[r] = (bf16)(acc2[mt][nt][r] + bias);
            int m0 = mt * 16 + quad * 4;
            *(bf16x4*)(Hw + n * 36 + m0) = pk;
        }
    }
    __syncthreads();

    // ---- epilogue: InstanceNorm + FiLM + skip ----
    const size_t xbase = (size_t)b * 64 * 65536 + (size_t)y * 256 + x0;
#pragma unroll
    for (int it = 0; it < 8; ++it) {
        int g = it * 256 + tid;
        int c = g >> 5;                       // 0..63
        int px = (g & 31) * 4;                // 0..124
        int wv = px >> 5, pm = px & 31;
        const bf16* GBv = buf + wv * 4608;
        bf16x4 gg = *(const bf16x4*)(GBv + c * 36 + pm);
        bf16x4 bb = *(const bf16x4*)(GBv + (c + 64) * 36 + pm);
        f32x4 xv = *(const f32x4*)(x + xbase + (size_t)c * 65536 + px);
        float mu = smean[c], rs = srstd[c];
        f32x4 o;
#pragma unroll
        for (int r = 0; r < 4; ++r) {
            float xn = (xv[r] - mu) * rs;
            o[r] = xn * (1.f + (float)gg[r]) + (float)bb[r] + 0.1f * xv[r];
        }
        *(f32x4*)(out + xbase + (size_t)c * 65536 + px) = o;
    }
}

// ---------------------------------------------------------------------------
extern "C" void kernel_launch(void* const* d_in, const int* in_sizes, int n_in,
                              void* d_out, int out_size, void* d_ws, size_t ws_size,
                              hipStream_t stream) {
    const float* x        = (const float*)d_in[0];
    const float* hm       = (const float*)d_in[1];
    const float* f2d      = (const float*)d_in[2];
    const float* w_shared = (const float*)d_in[3];
    const float* b_shared = (const float*)d_in[4];
    const float* w_gamma  = (const float*)d_in[5];
    const float* b_gamma  = (const float*)d_in[6];
    const float* w_beta   = (const float*)d_in[7];
    const float* b_beta   = (const float*)d_in[8];
    float* out = (float*)d_out;
    char* ws = (char*)d_ws;

    bf16*  hmd   = (bf16*)(ws + 0);             // 33,554,432 B
    bf16*  wsb   = (bf16*)(ws + 33554432);      // 8,192 B
    bf16*  wcat  = (bf16*)(ws + 33562624);      // 32,768 B
    float* meanp = (float*)(ws + 33595392);     // 2,048 B
    float* rstdp = (float*)(ws + 33597440);     // 2,048 B

    hipLaunchKernelGGL(k1_fused, dim3(512),  dim3(256), 0, stream, hm, f2d, hmd);
    hipLaunchKernelGGL(k0_prep,  dim3(64),   dim3(256), 0, stream, w_shared, w_gamma, w_beta, wsb, wcat);
    hipLaunchKernelGGL(k2_stats, dim3(512),  dim3(256), 0, stream, x, meanp, rstdp);
    hipLaunchKernelGGL(k3_fused, dim3(4096), dim3(256), 0, stream,
                       hmd, wsb, wcat, b_shared, b_gamma, b_beta, x, meanp, rstdp, out);
}

// Round 2
// 611.823 us; speedup vs baseline: 1.4914x; 1.0809x over previous
//
#include <hip/hip_runtime.h>
#include <cstdint>

typedef __bf16 bf16;
typedef bf16 bf16x4 __attribute__((ext_vector_type(4)));
typedef bf16 bf16x8 __attribute__((ext_vector_type(8)));
typedef float f32x4 __attribute__((ext_vector_type(4)));

// ---------------------------------------------------------------------------
// K1: fused separable 12-tap FIR downsample 512->256 (stride 2, pad 5, zeros)
//     + transpose-pack to split-plane NHWC bf16.
// Block tile: 8 output rows x 64 output cols x 8 channels.
// grid 4096 = b(8) x yt(32) x xt(4) x cg(4)
// out: hmd[plane cg][pixel][8ch] bf16, pixel = (b*256+y)*256+x, plane = 8 MiB
// taps: tv[j] = f2d[j][0], th[i] = f2d[0][i]/f2d[0][0]  (tv[j]*th[i]==f2d[j][i])
// ---------------------------------------------------------------------------
__global__ __launch_bounds__(256) void k1_fused(const float* __restrict__ hm,
                                                const float* __restrict__ f2d,
                                                bf16* __restrict__ hmd) {
    constexpr int IR = 148;            // padded row stride (floats), 592B (16B-aligned)
    __shared__ float in_t[26 * IR];    // 15,392 B  input tile (zero-padded)
    __shared__ float v_t[8 * IR];      //  4,736 B  after vertical pass
    __shared__ bf16  out_t[8 * 512];   //  8,192 B  8-channel transpose buffer
    // total 28,320 B -> 5 blocks/CU

    const int tid = threadIdx.x;
    const int bid = blockIdx.x;        // 4096
    const int cg = bid & 3;
    const int xt = (bid >> 2) & 3;
    const int yt = (bid >> 4) & 31;
    const int b  = bid >> 9;
    const int y0 = yt * 8;             // output row base
    const int x0 = xt * 64;            // output col base
    const int R0 = 2 * y0 - 5;         // input row of tile row 0
    const int B0 = 2 * x0 - 8;         // input col of tile col 0 (16B aligned)

    float tv[12], th[12];
    const float inv = 1.0f / f2d[0];
#pragma unroll
    for (int j = 0; j < 12; ++j) { tv[j] = f2d[j * 12]; th[j] = f2d[j] * inv; }

    const float* srcb = hm + (size_t)(b * 32 + cg * 8) * 262144;

#pragma unroll 1
    for (int ci = 0; ci < 8; ++ci) {
        const float* sc = srcb + (size_t)ci * 262144;

        // ---- stage 26 rows x 36 f32x4 chunks, zero-filled OOB ----
#pragma unroll
        for (int k = 0; k < 4; ++k) {
            int idx = k * 256 + tid;
            if (idx < 936) {
                int R = idx / 36;
                int q = idx - R * 36;
                int gr = R0 + R;
                int gc = B0 + 4 * q;           // 16B aligned; OOB all-or-nothing
                f32x4 vv = {0.f, 0.f, 0.f, 0.f};
                if ((unsigned)gr < 512u && (unsigned)gc < 512u)
                    vv = *(const f32x4*)(sc + gr * 512 + gc);
                *(f32x4*)(in_t + R * IR + 4 * q) = vv;
            }
        }
        __syncthreads();

        // ---- vertical FIR: 4 row-pairs x 36 chunks = 144 threads ----
        if (tid < 144) {
            int yp = tid / 36;                 // row pair 0..3
            int q  = tid - yp * 36;
            const float* col = in_t + 4 * q;
            f32x4 a0 = {0.f, 0.f, 0.f, 0.f};
            f32x4 a1 = {0.f, 0.f, 0.f, 0.f};
#pragma unroll
            for (int r = 0; r < 14; ++r) {
                f32x4 rv = *(const f32x4*)(col + (4 * yp + r) * IR);
                if (r < 12)  a0 += tv[r] * rv;
                if (r >= 2)  a1 += tv[r - 2] * rv;
            }
            *(f32x4*)(v_t + (2 * yp) * IR + 4 * q) = a0;
            *(f32x4*)(v_t + (2 * yp + 1) * IR + 4 * q) = a1;
        }
        __syncthreads();

        // ---- horizontal FIR: 2 output cols per thread, vectorized reads ----
        // 8 rows x 32 col-pairs = 256 threads
        {
            int xp = tid & 31;
            int yo = tid >> 5;
            const float* vr4 = v_t + yo * IR + 4 * xp;   // 16B aligned
            float arr[17];
            *(f32x4*)(arr + 0)  = *(const f32x4*)(vr4 + 0);
            *(f32x4*)(arr + 4)  = *(const f32x4*)(vr4 + 4);
            *(f32x4*)(arr + 8)  = *(const f32x4*)(vr4 + 8);
            *(f32x4*)(arr + 12) = *(const f32x4*)(vr4 + 12);
            arr[16] = vr4[16];
            float a0 = 0.f, a1 = 0.f;
#pragma unroll
            for (int r = 0; r < 12; ++r) {
                a0 += th[r] * arr[3 + r];
                a1 += th[r] * arr[5 + r];
            }
            unsigned lo = __builtin_bit_cast(unsigned short, (bf16)a0);
            unsigned hi = __builtin_bit_cast(unsigned short, (bf16)a1);
            *(unsigned int*)(out_t + ci * 512 + yo * 64 + 2 * xp) = lo | (hi << 16);
        }
        __syncthreads();   // out_t[ci] complete; also guards in_t overwrite
    }

    // ---- transpose-pack: one dense 16B store per pixel into plane cg ----
    const unsigned short* Ts = (const unsigned short*)out_t;
    bf16* plane = hmd + (size_t)cg * 4194304;
#pragma unroll
    for (int s = 0; s < 2; ++s) {
        int pix = s * 256 + tid;               // 0..511
        int yo = pix >> 6;
        int xo = pix & 63;
        unsigned int u[4];
#pragma unroll
        for (int g = 0; g < 4; ++g) {
            unsigned lo = Ts[(2 * g) * 512 + pix];
            unsigned hi = Ts[(2 * g + 1) * 512 + pix];
            u[g] = lo | (hi << 16);
        }
        size_t p = ((size_t)(b * 256 + y0 + yo) * 256) + x0 + xo;
        *(uint4*)(plane + p * 8) = make_uint4(u[0], u[1], u[2], u[3]);
    }
}

// ---------------------------------------------------------------------------
// K0: weights -> bf16.  wsb[n][k] n<128,k<32 ; wcat[n][k] n<128,k<128
// ---------------------------------------------------------------------------
__global__ __launch_bounds__(256) void k0_prep(const float* __restrict__ w_shared,
                                               const float* __restrict__ w_gamma,
                                               const float* __restrict__ w_beta,
                                               bf16* __restrict__ wsb,
                                               bf16* __restrict__ wcat) {
    int t = blockIdx.x * 256 + threadIdx.x;   // 16384 total
    if (t < 4096) wsb[t] = (bf16)w_shared[t];
    int n = t >> 7, k = t & 127;
    float wv = (n < 64) ? w_gamma[n * 128 + k] : w_beta[(n - 64) * 128 + k];
    wcat[t] = (bf16)wv;
}

// ---------------------------------------------------------------------------
// K2: InstanceNorm stats. one block per (b,c); 65536 elems.
// ---------------------------------------------------------------------------
__global__ __launch_bounds__(256) void k2_stats(const float* __restrict__ x,
                                                float* __restrict__ meanp,
                                                float* __restrict__ rstdp) {
    int bc = blockIdx.x;
    const float* p = x + (size_t)bc * 65536;
    int tid = threadIdx.x;
    float s = 0.f, s2 = 0.f;
#pragma unroll 4
    for (int i = 0; i < 64; ++i) {
        f32x4 vv = *(const f32x4*)(p + (i * 256 + tid) * 4);
        s += vv[0] + vv[1] + vv[2] + vv[3];
        s2 += vv[0] * vv[0] + vv[1] * vv[1] + vv[2] * vv[2] + vv[3] * vv[3];
    }
#pragma unroll
    for (int off = 32; off > 0; off >>= 1) {
        s += __shfl_down(s, off);
        s2 += __shfl_down(s2, off);
    }
    __shared__ float red[8];
    int w = tid >> 6, lane = tid & 63;
    if (lane == 0) { red[w] = s; red[4 + w] = s2; }
    __syncthreads();
    if (tid == 0) {
        float S = red[0] + red[1] + red[2] + red[3];
        float S2 = red[4] + red[5] + red[6] + red[7];
        float mu = S * (1.f / 65536.f);
        float var = S2 * (1.f / 65536.f) - mu * mu;
        meanp[bc] = mu;
        rstdp[bc] = rsqrtf(var + 1e-5f);
    }
}

// ---------------------------------------------------------------------------
// K3: fused  h = lrelu(U*Ws^T + bs)*sqrt2 ; [gamma|beta] = h*Wcat^T + bias ;
//            out = (x-mu)*rstd*(1+gamma) + beta + 0.1*x
// hmd is split-plane: plane[quad] + pixel*8 gives channels quad*8..quad*8+7
// ---------------------------------------------------------------------------
__global__ __launch_bounds__(256) void k3_fused(
    const bf16* __restrict__ hmd, const bf16* __restrict__ wsb,
    const bf16* __restrict__ wcat, const float* __restrict__ bsh,
    const float* __restrict__ bga, const float* __restrict__ bbe,
    const float* __restrict__ x, const float* __restrict__ meanp,
    const float* __restrict__ rstdp, float* __restrict__ out) {
    constexpr int HROW = 136;                 // bf16 units; 272B rows, 16B-aligned frags
    __shared__ bf16 buf[4 * 4608];            // per-wave: H[32][136] then GB[128][36]
    __shared__ float smean[64], srstd[64];

    const int tid = threadIdx.x;
    const int w = tid >> 6;
    const int lane = tid & 63;
    const int l15 = lane & 15;
    const int quad = lane >> 4;

    const int bid = blockIdx.x;               // 4096 blocks
    const int b = bid >> 9;
    const int y = (bid >> 1) & 255;
    const int x0 = (bid & 1) << 7;

    if (tid < 64) {
        smean[tid] = meanp[b * 64 + tid];
        srstd[tid] = rstdp[b * 64 + tid];
    }

    bf16* Hw = buf + w * 4608;
    const int pw = bid * 128 + w * 32;        // wave's pixel base

    // ---- GEMM1: K=32, one MFMA per (mt,nt) tile ----
    const bf16* plane = hmd + (size_t)quad * 4194304;
    bf16x8 a1[2];
#pragma unroll
    for (int mt = 0; mt < 2; ++mt)
        a1[mt] = *(const bf16x8*)(plane + (size_t)(pw + mt * 16 + l15) * 8);
    bf16x8 b1[8];
#pragma unroll
    for (int nt = 0; nt < 8; ++nt)
        b1[nt] = *(const bf16x8*)(wsb + (nt * 16 + l15) * 32 + quad * 8);
    f32x4 zero4 = {0.f, 0.f, 0.f, 0.f};
    f32x4 acc[2][8];
#pragma unroll
    for (int mt = 0; mt < 2; ++mt)
#pragma unroll
        for (int nt = 0; nt < 8; ++nt)
            acc[mt][nt] = __builtin_amdgcn_mfma_f32_16x16x32_bf16(a1[mt], b1[nt], zero4, 0, 0, 0);

    // bias + lrelu*sqrt2 -> H in LDS (C-frag -> A-frag layout transform)
#pragma unroll
    for (int nt = 0; nt < 8; ++nt) {
        float bs = bsh[nt * 16 + l15];
#pragma unroll
        for (int mt = 0; mt < 2; ++mt) {
#pragma unroll
            for (int r = 0; r < 4; ++r) {
                float hv = acc[mt][nt][r] + bs;
                hv = (hv >= 0.f ? hv : 0.2f * hv) * 1.41421356237309515f;
                int m = mt * 16 + quad * 4 + r;
                Hw[m * HROW + nt * 16 + l15] = (bf16)hv;
            }
        }
    }

    // ---- GEMM2: K=128 over 4 kt steps ----
    f32x4 acc2[2][8];
#pragma unroll
    for (int mt = 0; mt < 2; ++mt)
#pragma unroll
        for (int nt = 0; nt < 8; ++nt) acc2[mt][nt] = zero4;
#pragma unroll 1
    for (int kt = 0; kt < 4; ++kt) {
        bf16x8 b2[8];
#pragma unroll
        for (int nt = 0; nt < 8; ++nt)
            b2[nt] = *(const bf16x8*)(wcat + (nt * 16 + l15) * 128 + kt * 32 + quad * 8);
        bf16x8 a2[2];
#pragma unroll
        for (int mt = 0; mt < 2; ++mt)
            a2[mt] = *(const bf16x8*)(Hw + (mt * 16 + l15) * HROW + kt * 32 + quad * 8);
#pragma unroll
        for (int mt = 0; mt < 2; ++mt)
#pragma unroll
            for (int nt = 0; nt < 8; ++nt)
                acc2[mt][nt] = __builtin_amdgcn_mfma_f32_16x16x32_bf16(a2[mt], b2[nt], acc2[mt][nt], 0, 0, 0);
    }

    // gamma/beta (+bias) -> LDS bf16, layout GB[c][px_in_wave], row stride 36
#pragma unroll
    for (int nt = 0; nt < 8; ++nt) {
        int n = nt * 16 + l15;
        float bias = (n < 64) ? bga[n] : bbe[n - 64];
#pragma unroll
        for (int mt = 0; mt < 2; ++mt) {
            bf16x4 pk;
#pragma unroll
            for (int r = 0; r < 4; ++r) pk[r] = (bf16)(acc2[mt][nt][r] + bias);
            int m0 = mt * 16 + quad * 4;
            *(bf16x4*)(Hw + n * 36 + m0) = pk;
        }
    }
    __syncthreads();

    // ---- epilogue: InstanceNorm + FiLM + skip ----
    const size_t xbase = (size_t)b * 64 * 65536 + (size_t)y * 256 + x0;
#pragma unroll
    for (int it = 0; it < 8; ++it) {
        int g = it * 256 + tid;
        int c = g >> 5;                       // 0..63
        int px = (g & 31) * 4;                // 0..124
        int wv = px >> 5, pm = px & 31;
        const bf16* GBv = buf + wv * 4608;
        bf16x4 gg = *(const bf16x4*)(GBv + c * 36 + pm);
        bf16x4 bb = *(const bf16x4*)(GBv + (c + 64) * 36 + pm);
        f32x4 xv = *(const f32x4*)(x + xbase + (size_t)c * 65536 + px);
        float mu = smean[c], rs = srstd[c];
        f32x4 o;
#pragma unroll
        for (int r = 0; r < 4; ++r) {
            float xn = (xv[r] - mu) * rs;
            o[r] = xn * (1.f + (float)gg[r]) + (float)bb[r] + 0.1f * xv[r];
        }
        *(f32x4*)(out + xbase + (size_t)c * 65536 + px) = o;
    }
}

// ---------------------------------------------------------------------------
extern "C" void kernel_launch(void* const* d_in, const int* in_sizes, int n_in,
                              void* d_out, int out_size, void* d_ws, size_t ws_size,
                              hipStream_t stream) {
    const float* x        = (const float*)d_in[0];
    const float* hm       = (const float*)d_in[1];
    const float* f2d      = (const float*)d_in[2];
    const float* w_shared = (const float*)d_in[3];
    const float* b_shared = (const float*)d_in[4];
    const float* w_gamma  = (const float*)d_in[5];
    const float* b_gamma  = (const float*)d_in[6];
    const float* w_beta   = (const float*)d_in[7];
    const float* b_beta   = (const float*)d_in[8];
    float* out = (float*)d_out;
    char* ws = (char*)d_ws;

    bf16*  hmd   = (bf16*)(ws + 0);             // 33,554,432 B (4 planes x 8 MiB)
    bf16*  wsb   = (bf16*)(ws + 33554432);      // 8,192 B
    bf16*  wcat  = (bf16*)(ws + 33562624);      // 32,768 B
    float* meanp = (float*)(ws + 33595392);     // 2,048 B
    float* rstdp = (float*)(ws + 33597440);     // 2,048 B

    hipLaunchKernelGGL(k1_fused, dim3(4096), dim3(256), 0, stream, hm, f2d, hmd);
    hipLaunchKernelGGL(k0_prep,  dim3(64),   dim3(256), 0, stream, w_shared, w_gamma, w_beta, wsb, wcat);
    hipLaunchKernelGGL(k2_stats, dim3(512),  dim3(256), 0, stream, x, meanp, rstdp);
    hipLaunchKernelGGL(k3_fused, dim3(4096), dim3(256), 0, stream,
                       hmd, wsb, wcat, b_shared, b_gamma, b_beta, x, meanp, rstdp, out);
}

// Round 3
// 605.512 us; speedup vs baseline: 1.5070x; 1.0104x over previous
//
#include <hip/hip_runtime.h>
#include <cstdint>

typedef __bf16 bf16;
typedef bf16 bf16x4 __attribute__((ext_vector_type(4)));
typedef bf16 bf16x8 __attribute__((ext_vector_type(8)));
typedef float f32x4 __attribute__((ext_vector_type(4)));

// ---------------------------------------------------------------------------
// MEGA kernel: independent stages fused into one dispatch for concurrency.
//   blocks [0,64)    : k0  weights -> bf16
//   blocks [64,576)  : k2  InstanceNorm stats (one block per (b,c))
//   blocks [576,4672): k1  FIR downsample + transpose-pack (split-plane NHWC)
// All stages are data-independent; k3 (separate launch) consumes their outputs.
// ---------------------------------------------------------------------------
__global__ __launch_bounds__(256) void mega(
    const float* __restrict__ hm, const float* __restrict__ f2d,
    bf16* __restrict__ hmd,
    const float* __restrict__ x, float* __restrict__ meanp,
    float* __restrict__ rstdp,
    const float* __restrict__ w_shared, const float* __restrict__ w_gamma,
    const float* __restrict__ w_beta, bf16* __restrict__ wsb,
    bf16* __restrict__ wcat) {
    // shared LDS arena: k1 uses all 28,320 B; k2 overlays 32 B
    constexpr int IR = 148;                  // padded row stride (floats)
    __shared__ __align__(16) char smem[28320];

    const int tid = threadIdx.x;
    const int bid = blockIdx.x;

    if (bid < 64) {
        // ---------------- k0: weight conversion ----------------
        int t = bid * 256 + tid;             // 16384 total
        if (t < 4096) wsb[t] = (bf16)w_shared[t];
        int n = t >> 7, k = t & 127;
        float wv = (n < 64) ? w_gamma[n * 128 + k] : w_beta[(n - 64) * 128 + k];
        wcat[t] = (bf16)wv;
        return;
    }

    if (bid < 576) {
        // ---------------- k2: InstanceNorm stats ----------------
        int bc = bid - 64;                   // 0..511
        const float* p = x + (size_t)bc * 65536;
        float s = 0.f, s2 = 0.f;
#pragma unroll 4
        for (int i = 0; i < 64; ++i) {
            f32x4 vv = *(const f32x4*)(p + (i * 256 + tid) * 4);
            s += vv[0] + vv[1] + vv[2] + vv[3];
            s2 += vv[0] * vv[0] + vv[1] * vv[1] + vv[2] * vv[2] + vv[3] * vv[3];
        }
#pragma unroll
        for (int off = 32; off > 0; off >>= 1) {
            s += __shfl_down(s, off);
            s2 += __shfl_down(s2, off);
        }
        float* red = (float*)smem;
        int w = tid >> 6, lane = tid & 63;
        if (lane == 0) { red[w] = s; red[4 + w] = s2; }
        __syncthreads();
        if (tid == 0) {
            float S = red[0] + red[1] + red[2] + red[3];
            float S2 = red[4] + red[5] + red[6] + red[7];
            float mu = S * (1.f / 65536.f);
            float var = S2 * (1.f / 65536.f) - mu * mu;
            meanp[bc] = mu;
            rstdp[bc] = rsqrtf(var + 1e-5f);
        }
        return;
    }

    // ---------------- k1: fused separable FIR downsample ----------------
    float* in_t = (float*)smem;              // 26*IR floats = 15,392 B
    float* v_t  = (float*)(smem + 15392);    //  8*IR floats =  4,736 B
    bf16* out_t = (bf16*)(smem + 20128);     //  8*512 bf16  =  8,192 B

    const int kb = bid - 576;                // 0..4095
    const int cg = kb & 3;
    const int xt = (kb >> 2) & 3;
    const int yt = (kb >> 4) & 31;
    const int b  = kb >> 9;
    const int y0 = yt * 8;                   // output row base
    const int x0 = xt * 64;                  // output col base
    const int R0 = 2 * y0 - 5;               // input row of tile row 0
    const int B0 = 2 * x0 - 8;               // input col of tile col 0 (16B aligned)

    float tv[12], th[12];
    const float inv = 1.0f / f2d[0];
#pragma unroll
    for (int j = 0; j < 12; ++j) { tv[j] = f2d[j * 12]; th[j] = f2d[j] * inv; }

    const float* srcb = hm + (size_t)(b * 32 + cg * 8) * 262144;

#pragma unroll 1
    for (int ci = 0; ci < 8; ++ci) {
        const float* sc = srcb + (size_t)ci * 262144;

        // ---- stage 26 rows x 36 f32x4 chunks, zero-filled OOB ----
#pragma unroll
        for (int k = 0; k < 4; ++k) {
            int idx = k * 256 + tid;
            if (idx < 936) {
                int R = idx / 36;
                int q = idx - R * 36;
                int gr = R0 + R;
                int gc = B0 + 4 * q;         // 16B aligned; OOB all-or-nothing
                f32x4 vv = {0.f, 0.f, 0.f, 0.f};
                if ((unsigned)gr < 512u && (unsigned)gc < 512u)
                    vv = *(const f32x4*)(sc + gr * 512 + gc);
                *(f32x4*)(in_t + R * IR + 4 * q) = vv;
            }
        }
        __syncthreads();

        // ---- vertical FIR: 4 row-pairs x 36 chunks = 144 threads ----
        if (tid < 144) {
            int yp = tid / 36;               // row pair 0..3
            int q  = tid - yp * 36;
            const float* col = in_t + 4 * q;
            f32x4 a0 = {0.f, 0.f, 0.f, 0.f};
            f32x4 a1 = {0.f, 0.f, 0.f, 0.f};
#pragma unroll
            for (int r = 0; r < 14; ++r) {
                f32x4 rv = *(const f32x4*)(col + (4 * yp + r) * IR);
                if (r < 12)  a0 += tv[r] * rv;
                if (r >= 2)  a1 += tv[r - 2] * rv;
            }
            *(f32x4*)(v_t + (2 * yp) * IR + 4 * q) = a0;
            *(f32x4*)(v_t + (2 * yp + 1) * IR + 4 * q) = a1;
        }
        __syncthreads();

        // ---- horizontal FIR: 2 output cols per thread, vectorized reads ----
        {
            int xp = tid & 31;
            int yo = tid >> 5;
            const float* vr4 = v_t + yo * IR + 4 * xp;   // 16B aligned
            float arr[17];
            *(f32x4*)(arr + 0)  = *(const f32x4*)(vr4 + 0);
            *(f32x4*)(arr + 4)  = *(const f32x4*)(vr4 + 4);
            *(f32x4*)(arr + 8)  = *(const f32x4*)(vr4 + 8);
            *(f32x4*)(arr + 12) = *(const f32x4*)(vr4 + 12);
            arr[16] = vr4[16];
            float a0 = 0.f, a1 = 0.f;
#pragma unroll
            for (int r = 0; r < 12; ++r) {
                a0 += th[r] * arr[3 + r];
                a1 += th[r] * arr[5 + r];
            }
            unsigned lo = __builtin_bit_cast(unsigned short, (bf16)a0);
            unsigned hi = __builtin_bit_cast(unsigned short, (bf16)a1);
            *(unsigned int*)(out_t + ci * 512 + yo * 64 + 2 * xp) = lo | (hi << 16);
        }
        __syncthreads();   // out_t[ci] complete; also guards in_t overwrite
    }

    // ---- transpose-pack: one dense 16B store per pixel into plane cg ----
    const unsigned short* Ts = (const unsigned short*)out_t;
    bf16* plane = hmd + (size_t)cg * 4194304;
#pragma unroll
    for (int s = 0; s < 2; ++s) {
        int pix = s * 256 + tid;             // 0..511
        int yo = pix >> 6;
        int xo = pix & 63;
        unsigned int u[4];
#pragma unroll
        for (int g = 0; g < 4; ++g) {
            unsigned lo = Ts[(2 * g) * 512 + pix];
            unsigned hi = Ts[(2 * g + 1) * 512 + pix];
            u[g] = lo | (hi << 16);
        }
        size_t p = ((size_t)(b * 256 + y0 + yo) * 256) + x0 + xo;
        *(uint4*)(plane + p * 8) = make_uint4(u[0], u[1], u[2], u[3]);
    }
}

// ---------------------------------------------------------------------------
// K3: fused  h = lrelu(U*Ws^T + bs)*sqrt2 ; [gamma|beta] = h*Wcat^T + bias ;
//            out = (x-mu)*rstd*(1+gamma) + beta + 0.1*x
// hmd is split-plane: plane[quad] + pixel*8 gives channels quad*8..quad*8+7
// ---------------------------------------------------------------------------
__global__ __launch_bounds__(256) void k3_fused(
    const bf16* __restrict__ hmd, const bf16* __restrict__ wsb,
    const bf16* __restrict__ wcat, const float* __restrict__ bsh,
    const float* __restrict__ bga, const float* __restrict__ bbe,
    const float* __restrict__ x, const float* __restrict__ meanp,
    const float* __restrict__ rstdp, float* __restrict__ out) {
    constexpr int HROW = 136;                 // bf16 units; 272B rows, 16B-aligned frags
    __shared__ bf16 buf[4 * 4608];            // per-wave: H[32][136] then GB[128][36]
    __shared__ float smean[64], srstd[64];

    const int tid = threadIdx.x;
    const int w = tid >> 6;
    const int lane = tid & 63;
    const int l15 = lane & 15;
    const int quad = lane >> 4;

    const int bid = blockIdx.x;               // 4096 blocks
    const int b = bid >> 9;
    const int y = (bid >> 1) & 255;
    const int x0 = (bid & 1) << 7;

    if (tid < 64) {
        smean[tid] = meanp[b * 64 + tid];
        srstd[tid] = rstdp[b * 64 + tid];
    }

    bf16* Hw = buf + w * 4608;
    const int pw = bid * 128 + w * 32;        // wave's pixel base

    // ---- GEMM1: K=32, one MFMA per (mt,nt) tile ----
    const bf16* plane = hmd + (size_t)quad * 4194304;
    bf16x8 a1[2];
#pragma unroll
    for (int mt = 0; mt < 2; ++mt)
        a1[mt] = *(const bf16x8*)(plane + (size_t)(pw + mt * 16 + l15) * 8);
    bf16x8 b1[8];
#pragma unroll
    for (int nt = 0; nt < 8; ++nt)
        b1[nt] = *(const bf16x8*)(wsb + (nt * 16 + l15) * 32 + quad * 8);
    f32x4 zero4 = {0.f, 0.f, 0.f, 0.f};
    f32x4 acc[2][8];
#pragma unroll
    for (int mt = 0; mt < 2; ++mt)
#pragma unroll
        for (int nt = 0; nt < 8; ++nt)
            acc[mt][nt] = __builtin_amdgcn_mfma_f32_16x16x32_bf16(a1[mt], b1[nt], zero4, 0, 0, 0);

    // bias + lrelu*sqrt2 -> H in LDS (C-frag -> A-frag layout transform)
#pragma unroll
    for (int nt = 0; nt < 8; ++nt) {
        float bs = bsh[nt * 16 + l15];
#pragma unroll
        for (int mt = 0; mt < 2; ++mt) {
#pragma unroll
            for (int r = 0; r < 4; ++r) {
                float hv = acc[mt][nt][r] + bs;
                hv = (hv >= 0.f ? hv : 0.2f * hv) * 1.41421356237309515f;
                int m = mt * 16 + quad * 4 + r;
                Hw[m * HROW + nt * 16 + l15] = (bf16)hv;
            }
        }
    }

    // ---- GEMM2: K=128 over 4 kt steps ----
    f32x4 acc2[2][8];
#pragma unroll
    for (int mt = 0; mt < 2; ++mt)
#pragma unroll
        for (int nt = 0; nt < 8; ++nt) acc2[mt][nt] = zero4;
#pragma unroll 1
    for (int kt = 0; kt < 4; ++kt) {
        bf16x8 b2[8];
#pragma unroll
        for (int nt = 0; nt < 8; ++nt)
            b2[nt] = *(const bf16x8*)(wcat + (nt * 16 + l15) * 128 + kt * 32 + quad * 8);
        bf16x8 a2[2];
#pragma unroll
        for (int mt = 0; mt < 2; ++mt)
            a2[mt] = *(const bf16x8*)(Hw + (mt * 16 + l15) * HROW + kt * 32 + quad * 8);
#pragma unroll
        for (int mt = 0; mt < 2; ++mt)
#pragma unroll
            for (int nt = 0; nt < 8; ++nt)
                acc2[mt][nt] = __builtin_amdgcn_mfma_f32_16x16x32_bf16(a2[mt], b2[nt], acc2[mt][nt], 0, 0, 0);
    }

    // gamma/beta (+bias) -> LDS bf16, layout GB[c][px_in_wave], row stride 36
#pragma unroll
    for (int nt = 0; nt < 8; ++nt) {
        int n = nt * 16 + l15;
        float bias = (n < 64) ? bga[n] : bbe[n - 64];
#pragma unroll
        for (int mt = 0; mt < 2; ++mt) {
            bf16x4 pk;
#pragma unroll
            for (int r = 0; r < 4; ++r) pk[r] = (bf16)(acc2[mt][nt][r] + bias);
            int m0 = mt * 16 + quad * 4;
            *(bf16x4*)(Hw + n * 36 + m0) = pk;
        }
    }
    __syncthreads();

    // ---- epilogue: InstanceNorm + FiLM + skip ----
    const size_t xbase = (size_t)b * 64 * 65536 + (size_t)y * 256 + x0;
#pragma unroll
    for (int it = 0; it < 8; ++it) {
        int g = it * 256 + tid;
        int c = g >> 5;                       // 0..63
        int px = (g & 31) * 4;                // 0..124
        int wv = px >> 5, pm = px & 31;
        const bf16* GBv = buf + wv * 4608;
        bf16x4 gg = *(const bf16x4*)(GBv + c * 36 + pm);
        bf16x4 bb = *(const bf16x4*)(GBv + (c + 64) * 36 + pm);
        f32x4 xv = *(const f32x4*)(x + xbase + (size_t)c * 65536 + px);
        float mu = smean[c], rs = srstd[c];
        f32x4 o;
#pragma unroll
        for (int r = 0; r < 4; ++r) {
            float xn = (xv[r] - mu) * rs;
            o[r] = xn * (1.f + (float)gg[r]) + (float)bb[r] + 0.1f * xv[r];
        }
        *(f32x4*)(out + xbase + (size_t)c * 65536 + px) = o;
    }
}

// ---------------------------------------------------------------------------
extern "C" void kernel_launch(void* const* d_in, const int* in_sizes, int n_in,
                              void* d_out, int out_size, void* d_ws, size_t ws_size,
                              hipStream_t stream) {
    const float* x        = (const float*)d_in[0];
    const float* hm       = (const float*)d_in[1];
    const float* f2d      = (const float*)d_in[2];
    const float* w_shared = (const float*)d_in[3];
    const float* b_shared = (const float*)d_in[4];
    const float* w_gamma  = (const float*)d_in[5];
    const float* b_gamma  = (const float*)d_in[6];
    const float* w_beta   = (const float*)d_in[7];
    const float* b_beta   = (const float*)d_in[8];
    float* out = (float*)d_out;
    char* ws = (char*)d_ws;

    bf16*  hmd   = (bf16*)(ws + 0);             // 33,554,432 B (4 planes x 8 MiB)
    bf16*  wsb   = (bf16*)(ws + 33554432);      // 8,192 B
    bf16*  wcat  = (bf16*)(ws + 33562624);      // 32,768 B
    float* meanp = (float*)(ws + 33595392);     // 2,048 B
    float* rstdp = (float*)(ws + 33597440);     // 2,048 B

    hipLaunchKernelGGL(mega, dim3(4672), dim3(256), 0, stream,
                       hm, f2d, hmd, x, meanp, rstdp,
                       w_shared, w_gamma, w_beta, wsb, wcat);
    hipLaunchKernelGGL(k3_fused, dim3(4096), dim3(256), 0, stream,
                       hmd, wsb, wcat, b_shared, b_gamma, b_beta, x, meanp, rstdp, out);
}